// Round 1
// baseline (81.767 us; speedup 1.0000x reference)
//
#include <hip/hip_runtime.h>

#define Ndim 128
#define Cdim 3
#define Hdim 256
#define Wdim 256
#define MAXNORM_D 5.371920351148152

__device__ __forceinline__ void mm3(const double a[3][3], const double b[3][3], double c[3][3]) {
    #pragma unroll
    for (int i = 0; i < 3; ++i)
        #pragma unroll
        for (int j = 0; j < 3; ++j) {
            double s = 0.0;
            #pragma unroll
            for (int k = 0; k < 3; ++k) s += a[i][k] * b[k][j];
            c[i][j] = s;
        }
}

// One thread per batch element: expm of padded 3x3 affine matrix, write top 2 rows.
__global__ void expm_kernel(const float* __restrict__ theta, float* __restrict__ thOut) {
    int n = blockIdx.x * blockDim.x + threadIdx.x;
    if (n >= Ndim) return;

    const double b[14] = {6.476475253248e+16, 3.238237626624e+16, 7771770303897600.0,
                          1187353796428800.0, 129060195264000.0, 10559470521600.0,
                          670442572800.0, 33522128640.0, 1323241920.0, 40840800.0,
                          960960.0, 16380.0, 182.0, 1.0};

    double A[3][3];
    #pragma unroll
    for (int j = 0; j < 3; ++j) {
        A[0][j] = (double)theta[n * 6 + j];
        A[1][j] = (double)theta[n * 6 + 3 + j];
        A[2][j] = 0.0;
    }

    double fro2 = 0.0;
    #pragma unroll
    for (int i = 0; i < 3; ++i)
        #pragma unroll
        for (int j = 0; j < 3; ++j) fro2 += A[i][j] * A[i][j];
    double fro = sqrt(fro2);

    double nsq = fmax(0.0, ceil(log2(fro / MAXNORM_D)));
    int k = (int)nsq;
    double sc = exp2(-nsq);
    #pragma unroll
    for (int i = 0; i < 3; ++i)
        #pragma unroll
        for (int j = 0; j < 3; ++j) A[i][j] *= sc;

    double A2[3][3], A4[3][3], A6[3][3], P[3][3], Wm[3][3], T[3][3], U[3][3], V[3][3];
    mm3(A, A, A2);
    mm3(A2, A2, A4);
    mm3(A4, A2, A6);

    #pragma unroll
    for (int i = 0; i < 3; ++i)
        #pragma unroll
        for (int j = 0; j < 3; ++j)
            P[i][j] = b[13] * A6[i][j] + b[11] * A4[i][j] + b[9] * A2[i][j];
    mm3(A6, P, T);
    #pragma unroll
    for (int i = 0; i < 3; ++i)
        #pragma unroll
        for (int j = 0; j < 3; ++j)
            Wm[i][j] = T[i][j] + b[7] * A6[i][j] + b[5] * A4[i][j] + b[3] * A2[i][j]
                       + (i == j ? b[1] : 0.0);
    mm3(A, Wm, U);

    #pragma unroll
    for (int i = 0; i < 3; ++i)
        #pragma unroll
        for (int j = 0; j < 3; ++j)
            P[i][j] = b[12] * A6[i][j] + b[10] * A4[i][j] + b[8] * A2[i][j];
    mm3(A6, P, T);
    #pragma unroll
    for (int i = 0; i < 3; ++i)
        #pragma unroll
        for (int j = 0; j < 3; ++j)
            V[i][j] = T[i][j] + b[6] * A6[i][j] + b[4] * A4[i][j] + b[2] * A2[i][j]
                      + (i == j ? b[0] : 0.0);

    // Solve (U+V) X = (V-U) : Gauss-Jordan with partial pivoting on [M | RHS]
    double M[3][6];
    #pragma unroll
    for (int i = 0; i < 3; ++i)
        #pragma unroll
        for (int j = 0; j < 3; ++j) {
            M[i][j]     = U[i][j] + V[i][j];
            M[i][j + 3] = V[i][j] - U[i][j];
        }
    #pragma unroll
    for (int col = 0; col < 3; ++col) {
        int piv = col;
        double best = fabs(M[col][col]);
        for (int r = col + 1; r < 3; ++r) {
            double v = fabs(M[r][col]);
            if (v > best) { best = v; piv = r; }
        }
        if (piv != col) {
            #pragma unroll
            for (int j = 0; j < 6; ++j) {
                double t = M[col][j]; M[col][j] = M[piv][j]; M[piv][j] = t;
            }
        }
        double inv = 1.0 / M[col][col];
        #pragma unroll
        for (int j = 0; j < 6; ++j) M[col][j] *= inv;
        #pragma unroll
        for (int r = 0; r < 3; ++r) {
            if (r == col) continue;
            double f = M[r][col];
            #pragma unroll
            for (int j = 0; j < 6; ++j) M[r][j] -= f * M[col][j];
        }
    }
    double R[3][3];
    #pragma unroll
    for (int i = 0; i < 3; ++i)
        #pragma unroll
        for (int j = 0; j < 3; ++j) R[i][j] = M[i][j + 3];

    for (int i = 0; i < 16; ++i) {
        if (i < k) {
            double Rn[3][3];
            mm3(R, R, Rn);
            #pragma unroll
            for (int a = 0; a < 3; ++a)
                #pragma unroll
                for (int c = 0; c < 3; ++c) R[a][c] = Rn[a][c];
        }
    }

    #pragma unroll
    for (int j = 0; j < 3; ++j) {
        thOut[n * 6 + j]     = (float)R[0][j];
        thOut[n * 6 + 3 + j] = (float)R[1][j];
    }
}

// Fused affine_grid + bilinear grid_sample (zeros padding, align_corners=True).
// One thread per (n,h,w); loops over C channels (coords shared across channels).
__global__ __launch_bounds__(256) void sample_kernel(const float* __restrict__ x,
                                                     const float* __restrict__ th,
                                                     float* __restrict__ out) {
    int idx = blockIdx.x * 256 + threadIdx.x;
    int w = idx & (Wdim - 1);
    int h = (idx >> 8) & (Hdim - 1);
    int n = idx >> 16;

    const float* t = th + n * 6;
    float gx = fmaf((float)w, 2.0f / (float)(Wdim - 1), -1.0f);
    float gy = fmaf((float)h, 2.0f / (float)(Hdim - 1), -1.0f);

    float tx = fmaf(t[0], gx, fmaf(t[1], gy, t[2]));
    float ty = fmaf(t[3], gx, fmaf(t[4], gy, t[5]));

    float ix = (tx + 1.0f) * (0.5f * (float)(Wdim - 1));
    float iy = (ty + 1.0f) * (0.5f * (float)(Hdim - 1));

    float ix0f = floorf(ix), iy0f = floorf(iy);
    int ix0 = (int)ix0f, iy0 = (int)iy0f;
    int ix1 = ix0 + 1, iy1 = iy0 + 1;

    float wx1 = ix - ix0f, wx0 = 1.0f - wx1;
    float wy1 = iy - iy0f, wy0 = 1.0f - wy1;

    float mx0 = (ix0 >= 0 && ix0 < Wdim) ? 1.0f : 0.0f;
    float mx1 = (ix1 >= 0 && ix1 < Wdim) ? 1.0f : 0.0f;
    float my0 = (iy0 >= 0 && iy0 < Hdim) ? 1.0f : 0.0f;
    float my1 = (iy1 >= 0 && iy1 < Hdim) ? 1.0f : 0.0f;

    int xc0 = min(max(ix0, 0), Wdim - 1);
    int xc1 = min(max(ix1, 0), Wdim - 1);
    int yc0 = min(max(iy0, 0), Hdim - 1);
    int yc1 = min(max(iy1, 0), Hdim - 1);

    float w00 = wy0 * wx0 * my0 * mx0;
    float w01 = wy0 * wx1 * my0 * mx1;
    float w10 = wy1 * wx0 * my1 * mx0;
    float w11 = wy1 * wx1 * my1 * mx1;

    int o00 = yc0 * Wdim + xc0;
    int o01 = yc0 * Wdim + xc1;
    int o10 = yc1 * Wdim + xc0;
    int o11 = yc1 * Wdim + xc1;

    size_t nbase = (size_t)n * Cdim * (Hdim * Wdim);
    size_t opix  = (size_t)h * Wdim + w;

    #pragma unroll
    for (int c = 0; c < Cdim; ++c) {
        const float* img = x + nbase + (size_t)c * (Hdim * Wdim);
        float v00 = img[o00];
        float v01 = img[o01];
        float v10 = img[o10];
        float v11 = img[o11];
        float r = fmaf(v00, w00, fmaf(v01, w01, fmaf(v10, w10, v11 * w11)));
        out[nbase + (size_t)c * (Hdim * Wdim) + opix] = r;
    }
}

extern "C" void kernel_launch(void* const* d_in, const int* in_sizes, int n_in,
                              void* d_out, int out_size, void* d_ws, size_t ws_size,
                              hipStream_t stream) {
    const float* x     = (const float*)d_in[0];
    const float* theta = (const float*)d_in[1];
    float* out = (float*)d_out;
    float* th  = (float*)d_ws;  // 128*6 floats of scratch

    expm_kernel<<<1, 128, 0, stream>>>(theta, th);

    int total = Ndim * Hdim * Wdim;
    sample_kernel<<<total / 256, 256, 0, stream>>>(x, th, out);
}

// Round 2
// 68.980 us; speedup vs baseline: 1.1854x; 1.1854x over previous
//
#include <hip/hip_runtime.h>

#define Ndim 128
#define Cdim 3
#define Hdim 256
#define Wdim 256
#define MAXNORM_D 5.371920351148152

__device__ __forceinline__ void mm3(const double a[3][3], const double b[3][3], double c[3][3]) {
    #pragma unroll
    for (int i = 0; i < 3; ++i)
        #pragma unroll
        for (int j = 0; j < 3; ++j) {
            double s = 0.0;
            #pragma unroll
            for (int k = 0; k < 3; ++k) s += a[i][k] * b[k][j];
            c[i][j] = s;
        }
}

// One thread per batch element: expm of padded 3x3 affine matrix, write top 2 rows.
__global__ void expm_kernel(const float* __restrict__ theta, float* __restrict__ thOut) {
    int n = blockIdx.x * blockDim.x + threadIdx.x;
    if (n >= Ndim) return;

    const double b[14] = {6.476475253248e+16, 3.238237626624e+16, 7771770303897600.0,
                          1187353796428800.0, 129060195264000.0, 10559470521600.0,
                          670442572800.0, 33522128640.0, 1323241920.0, 40840800.0,
                          960960.0, 16380.0, 182.0, 1.0};

    double A[3][3];
    #pragma unroll
    for (int j = 0; j < 3; ++j) {
        A[0][j] = (double)theta[n * 6 + j];
        A[1][j] = (double)theta[n * 6 + 3 + j];
        A[2][j] = 0.0;
    }

    double fro2 = 0.0;
    #pragma unroll
    for (int i = 0; i < 3; ++i)
        #pragma unroll
        for (int j = 0; j < 3; ++j) fro2 += A[i][j] * A[i][j];
    double fro = sqrt(fro2);

    double nsq = fmax(0.0, ceil(log2(fro / MAXNORM_D)));
    int k = (int)nsq;
    double sc = exp2(-nsq);
    #pragma unroll
    for (int i = 0; i < 3; ++i)
        #pragma unroll
        for (int j = 0; j < 3; ++j) A[i][j] *= sc;

    double A2[3][3], A4[3][3], A6[3][3], P[3][3], Wm[3][3], T[3][3], U[3][3], V[3][3];
    mm3(A, A, A2);
    mm3(A2, A2, A4);
    mm3(A4, A2, A6);

    #pragma unroll
    for (int i = 0; i < 3; ++i)
        #pragma unroll
        for (int j = 0; j < 3; ++j)
            P[i][j] = b[13] * A6[i][j] + b[11] * A4[i][j] + b[9] * A2[i][j];
    mm3(A6, P, T);
    #pragma unroll
    for (int i = 0; i < 3; ++i)
        #pragma unroll
        for (int j = 0; j < 3; ++j)
            Wm[i][j] = T[i][j] + b[7] * A6[i][j] + b[5] * A4[i][j] + b[3] * A2[i][j]
                       + (i == j ? b[1] : 0.0);
    mm3(A, Wm, U);

    #pragma unroll
    for (int i = 0; i < 3; ++i)
        #pragma unroll
        for (int j = 0; j < 3; ++j)
            P[i][j] = b[12] * A6[i][j] + b[10] * A4[i][j] + b[8] * A2[i][j];
    mm3(A6, P, T);
    #pragma unroll
    for (int i = 0; i < 3; ++i)
        #pragma unroll
        for (int j = 0; j < 3; ++j)
            V[i][j] = T[i][j] + b[6] * A6[i][j] + b[4] * A4[i][j] + b[2] * A2[i][j]
                      + (i == j ? b[0] : 0.0);

    // Solve (U+V) X = (V-U) : Gauss-Jordan with partial pivoting on [M | RHS]
    double M[3][6];
    #pragma unroll
    for (int i = 0; i < 3; ++i)
        #pragma unroll
        for (int j = 0; j < 3; ++j) {
            M[i][j]     = U[i][j] + V[i][j];
            M[i][j + 3] = V[i][j] - U[i][j];
        }
    #pragma unroll
    for (int col = 0; col < 3; ++col) {
        int piv = col;
        double best = fabs(M[col][col]);
        for (int r = col + 1; r < 3; ++r) {
            double v = fabs(M[r][col]);
            if (v > best) { best = v; piv = r; }
        }
        if (piv != col) {
            #pragma unroll
            for (int j = 0; j < 6; ++j) {
                double t = M[col][j]; M[col][j] = M[piv][j]; M[piv][j] = t;
            }
        }
        double inv = 1.0 / M[col][col];
        #pragma unroll
        for (int j = 0; j < 6; ++j) M[col][j] *= inv;
        #pragma unroll
        for (int r = 0; r < 3; ++r) {
            if (r == col) continue;
            double f = M[r][col];
            #pragma unroll
            for (int j = 0; j < 6; ++j) M[r][j] -= f * M[col][j];
        }
    }
    double R[3][3];
    #pragma unroll
    for (int i = 0; i < 3; ++i)
        #pragma unroll
        for (int j = 0; j < 3; ++j) R[i][j] = M[i][j + 3];

    for (int i = 0; i < 16; ++i) {
        if (i < k) {
            double Rn[3][3];
            mm3(R, R, Rn);
            #pragma unroll
            for (int a = 0; a < 3; ++a)
                #pragma unroll
                for (int c = 0; c < 3; ++c) R[a][c] = Rn[a][c];
        }
    }

    #pragma unroll
    for (int j = 0; j < 3; ++j) {
        thOut[n * 6 + j]     = (float)R[0][j];
        thOut[n * 6 + 3 + j] = (float)R[1][j];
    }
}

// Fused affine_grid + bilinear grid_sample (zeros padding, align_corners=True).
// 2-D tiles: each 256-thread block covers a 64(w) x 4(h) output tile; each wave
// is one tile row (coalesced 256B stores). Bijective XCD swizzle so each XCD
// processes 16 whole images contiguously -> bilinear row-overlap reuse stays in
// the XCD-local L2 instead of re-fetching from HBM.
__global__ __launch_bounds__(256) void sample_kernel(const float* __restrict__ x,
                                                     const float* __restrict__ th,
                                                     float* __restrict__ out) {
    // nwg = 128 * 64 * 4 = 32768, divisible by 8 -> simple bijective swizzle
    const int nwg_per_xcd = (Ndim * (Hdim / 4) * (Wdim / 64)) / 8;  // 4096
    int bid = blockIdx.x;
    int wgid = (bid & 7) * nwg_per_xcd + (bid >> 3);

    int tw  = wgid & 3;          // tile col  (W/64 = 4)
    int thr = (wgid >> 2) & 63;  // tile row  (H/4  = 64)
    int n   = wgid >> 8;         // image

    int tid = threadIdx.x;
    int w = (tw << 6) + (tid & 63);
    int h = (thr << 2) + (tid >> 6);

    const float* t = th + n * 6;
    float gx = fmaf((float)w, 2.0f / (float)(Wdim - 1), -1.0f);
    float gy = fmaf((float)h, 2.0f / (float)(Hdim - 1), -1.0f);

    float tx = fmaf(t[0], gx, fmaf(t[1], gy, t[2]));
    float ty = fmaf(t[3], gx, fmaf(t[4], gy, t[5]));

    float ix = (tx + 1.0f) * (0.5f * (float)(Wdim - 1));
    float iy = (ty + 1.0f) * (0.5f * (float)(Hdim - 1));

    float ix0f = floorf(ix), iy0f = floorf(iy);
    int ix0 = (int)ix0f, iy0 = (int)iy0f;
    int ix1 = ix0 + 1, iy1 = iy0 + 1;

    float wx1 = ix - ix0f, wx0 = 1.0f - wx1;
    float wy1 = iy - iy0f, wy0 = 1.0f - wy1;

    float mx0 = (ix0 >= 0 && ix0 < Wdim) ? 1.0f : 0.0f;
    float mx1 = (ix1 >= 0 && ix1 < Wdim) ? 1.0f : 0.0f;
    float my0 = (iy0 >= 0 && iy0 < Hdim) ? 1.0f : 0.0f;
    float my1 = (iy1 >= 0 && iy1 < Hdim) ? 1.0f : 0.0f;

    int xc0 = min(max(ix0, 0), Wdim - 1);
    int xc1 = min(max(ix1, 0), Wdim - 1);
    int yc0 = min(max(iy0, 0), Hdim - 1);
    int yc1 = min(max(iy1, 0), Hdim - 1);

    float w00 = wy0 * wx0 * my0 * mx0;
    float w01 = wy0 * wx1 * my0 * mx1;
    float w10 = wy1 * wx0 * my1 * mx0;
    float w11 = wy1 * wx1 * my1 * mx1;

    int o00 = yc0 * Wdim + xc0;
    int o01 = yc0 * Wdim + xc1;
    int o10 = yc1 * Wdim + xc0;
    int o11 = yc1 * Wdim + xc1;

    size_t nbase = (size_t)n * Cdim * (Hdim * Wdim);
    size_t opix  = (size_t)h * Wdim + w;

    #pragma unroll
    for (int c = 0; c < Cdim; ++c) {
        const float* img = x + nbase + (size_t)c * (Hdim * Wdim);
        float v00 = img[o00];
        float v01 = img[o01];
        float v10 = img[o10];
        float v11 = img[o11];
        float r = fmaf(v00, w00, fmaf(v01, w01, fmaf(v10, w10, v11 * w11)));
        out[nbase + (size_t)c * (Hdim * Wdim) + opix] = r;
    }
}

extern "C" void kernel_launch(void* const* d_in, const int* in_sizes, int n_in,
                              void* d_out, int out_size, void* d_ws, size_t ws_size,
                              hipStream_t stream) {
    const float* x     = (const float*)d_in[0];
    const float* theta = (const float*)d_in[1];
    float* out = (float*)d_out;
    float* th  = (float*)d_ws;  // 128*6 floats of scratch

    expm_kernel<<<1, 128, 0, stream>>>(theta, th);

    int total_tiles = Ndim * (Hdim / 4) * (Wdim / 64);  // 32768
    sample_kernel<<<total_tiles, 256, 0, stream>>>(x, th, out);
}